// Round 1
// baseline (160.243 us; speedup 1.0000x reference)
//
#include <hip/hip_runtime.h>

// SemanticCaps dynamic routing, fp32. B=128, J=10, K=1152, M=16, I=8.
// R6: latency-bound fix. Ws tile staged to LDS once per block (no per-k
// scalar-chunk serialization), KT 9->3 so grid=768 (2 blocks/CU -> TLP
// covers the per-k softmax barrier), xT loads software-pipelined across k,
// squash re-parallelized (320 blocks, 4 waves fold per 64 outputs).
// b-logit algebra: b after t iters = u.(v0+..+v_{t-1}) (b starts at 0).
//
// ws (floats): xT[9216*128] sp[384*10*128*16] v0T[20480] vsumT[20480]

#define B_ 128
#define J_ 10
#define K_ 1152
#define M_ 16
#define I_ 8
#define KT 3
#define NKT (K_ / KT)     // 384 k-tiles
#define RW (K_ * I_)      // 9216 rows of xT
#define WTILE (KT * M_ * I_ / 4)   // 96 float4 per j-slice

// ---------- transpose x[b][k][i] -> xT[k*8+i][b] (LDS-tiled, coalesced) ----
__global__ __launch_bounds__(256)
void xpose_kernel(const float* __restrict__ x, float* __restrict__ xT) {
    __shared__ float tile[64 * 65];
    const int t = threadIdx.x;
    const int r0 = blockIdx.x * 64, b0 = blockIdx.y * 64;
    const int hi = t >> 6, lo = t & 63;
#pragma unroll 4
    for (int c = 0; c < 16; ++c) {
        const int bb = c * 4 + hi;
        tile[lo * 65 + bb] = x[(size_t)(b0 + bb) * RW + r0 + lo];
    }
    __syncthreads();
#pragma unroll 4
    for (int c = 0; c < 16; ++c) {
        const int r = c * 4 + hi;
        xT[(size_t)(r0 + r) * B_ + b0 + lo] = tile[r * 65 + lo];
    }
}

// ---------- routing iteration ------------------------------------------------
// MODE 0: c == 1 (iteration 0; 0.1 folded into squash<0>)
// MODE 1: c = softmax_j(u . vin);  s = sum_k c*u  (u stays in registers)
// Wave = output capsule j (10 waves), lane = batch b (64). Ws tile for the
// block's 3 k's lives in LDS; per-k reads are same-address broadcasts.
template <int MODE>
__global__ __launch_bounds__(640)
void iter_kernel(const float* __restrict__ xT, const float* __restrict__ Ws,
                 const float* __restrict__ vinT, float* __restrict__ sp) {
    __shared__ float4 wsT4[J_ * WTILE];      // 10*96 float4 = 15360 B
    __shared__ float earr[2][J_ * 64];       // softmax exchange, ping-pong
    const int t  = threadIdx.x;
    const int bl = t & 63;
    const int j  = t >> 6;
    const int kt = blockIdx.x, bg = blockIdx.y;
    const int b  = bg * 64 + bl;

    // stage this wave's own j-slice of Ws: KT*128 floats = 96 float4,
    // coalesced 16B/lane. No cross-wave LDS dependency (each wave reads
    // only its own slice), so no staging barrier is needed.
    {
        const float4* src = (const float4*)(Ws + ((size_t)j * K_ + (size_t)kt * KT) * (M_ * I_));
        float4* dst = wsT4 + j * WTILE;
        dst[bl] = src[bl];
        if (bl < WTILE - 64) dst[64 + bl] = src[64 + bl];
    }

    float v[M_], s[M_];
#pragma unroll
    for (int m = 0; m < M_; ++m) s[m] = 0.f;
    if (MODE == 1) {
        const float4* vp = (const float4*)(vinT + ((size_t)j * B_ + b) * M_);
#pragma unroll
        for (int q = 0; q < 4; ++q) {
            const float4 w = vp[q];
            v[q * 4] = w.x; v[q * 4 + 1] = w.y; v[q * 4 + 2] = w.z; v[q * 4 + 3] = w.w;
        }
    }

    // prefetch xr for kk=0
    float xr[I_];
#pragma unroll
    for (int i = 0; i < I_; ++i)
        xr[i] = xT[(size_t)((kt * KT) * I_ + i) * B_ + b];

#pragma unroll
    for (int kk = 0; kk < KT; ++kk) {
        const float4* wv4 = wsT4 + (j * KT + kk) * (M_ * I_ / 4);
        float u[M_];
#pragma unroll
        for (int m = 0; m < M_; ++m) {
            const float4 a4 = wv4[2 * m];
            const float4 b4 = wv4[2 * m + 1];
            u[m] = a4.x * xr[0] + a4.y * xr[1] + a4.z * xr[2] + a4.w * xr[3]
                 + b4.x * xr[4] + b4.y * xr[5] + b4.z * xr[6] + b4.w * xr[7];
        }

        // prefetch next k's x row before the barrier (hides L1/L2 latency
        // under the softmax exchange phase)
        float xn[I_];
        if (kk + 1 < KT) {
#pragma unroll
            for (int i = 0; i < I_; ++i)
                xn[i] = xT[(size_t)((kt * KT + kk + 1) * I_ + i) * B_ + b];
        }

        if (MODE == 1) {
            float lg = 0.f;
#pragma unroll
            for (int m = 0; m < M_; ++m) lg += u[m] * v[m];
            const float e = __expf(lg);
            earr[kk & 1][j * 64 + bl] = e;
            __syncthreads();   // one barrier/k; ping-pong makes reuse race-free
            float den = 0.f;
#pragma unroll
            for (int jj = 0; jj < J_; ++jj) den += earr[kk & 1][jj * 64 + bl];
            const float c = __fdividef(e, den);
#pragma unroll
            for (int m = 0; m < M_; ++m) s[m] += c * u[m];
        } else {
#pragma unroll
            for (int m = 0; m < M_; ++m) s[m] += u[m];
        }

        if (kk + 1 < KT) {
#pragma unroll
            for (int i = 0; i < I_; ++i) xr[i] = xn[i];
        }
    }

    float4* o = (float4*)(sp + (((size_t)kt * J_ + j) * B_ + b) * M_);
#pragma unroll
    for (int q = 0; q < 4; ++q) {
        float4 w;
        w.x = s[q * 4]; w.y = s[q * 4 + 1]; w.z = s[q * 4 + 2]; w.w = s[q * 4 + 3];
        o[q] = w;
    }
}

// ---------- squash: fold 384 coalesced tile-partials, emit v -----------------
// 320 blocks x 256 threads; 4 waves each sum 96 tiles for 64 outputs, LDS
// fold, wave 0 does the m-shuffle norm + emit.
// SM 0: v0T = squash(0.1*S)  SM 1: vsumT = v0T + squash(S)  SM 2: out = squash(S)
template <int SM>
__global__ __launch_bounds__(256)
void squash_kernel(const float* __restrict__ sp, const float* __restrict__ v0T,
                   float* __restrict__ dst) {
    __shared__ float red[4][64];
    const int t  = threadIdx.x;
    const int l  = t & 63;
    const int wv = t >> 6;
    const int g  = blockIdx.x * 64 + l;   // g = (j*128+b)*16+m
    const int m = g & 15;
    const int b = (g >> 4) & 127;
    const int j = g >> 11;
    const size_t stride = (size_t)J_ * B_ * M_;
    const float* p = sp + (size_t)((j * B_ + b) * M_ + m);
    float S = 0.f;
#pragma unroll 8
    for (int tt = wv * (NKT / 4); tt < (wv + 1) * (NKT / 4); ++tt)
        S += p[(size_t)tt * stride];
    red[wv][l] = S;
    __syncthreads();
    if (wv == 0) {
        S = red[0][l] + red[1][l] + red[2][l] + red[3][l];
        if (SM == 0) S *= 0.1f;
        float sq = S * S;
        sq += __shfl_xor(sq, 1, 64);
        sq += __shfl_xor(sq, 2, 64);
        sq += __shfl_xor(sq, 4, 64);
        sq += __shfl_xor(sq, 8, 64);
        const float n = sqrtf(sq);
        float v = S * (n / (1.f + sq));
        if (SM == 1) v += v0T[g];
        if (SM == 2) dst[((size_t)b * J_ + j) * M_ + m] = v;   // standard [b][j][m]
        else         dst[g] = v;                                // vT layout
    }
}

extern "C" void kernel_launch(void* const* d_in, const int* in_sizes, int n_in,
                              void* d_out, int out_size, void* d_ws, size_t ws_size,
                              hipStream_t stream) {
    const float* x  = (const float*)d_in[0];   // [128][1152][8]
    const float* Ws = (const float*)d_in[1];   // [10][1152][16][8]
    float* out = (float*)d_out;                // [128][10][16]

    float* xT    = (float*)d_ws;                           // 1,179,648
    float* sp    = xT + (size_t)RW * B_;                   // 7,864,320
    float* v0T   = sp + (size_t)NKT * J_ * B_ * M_;        //    20,480
    float* vsumT = v0T + J_ * B_ * M_;                     //    20,480

    xpose_kernel<<<dim3(RW / 64, 2), 256, 0, stream>>>(x, xT);

    iter_kernel<0><<<dim3(NKT, 2), 640, 0, stream>>>(xT, Ws, nullptr, sp);
    squash_kernel<0><<<320, 256, 0, stream>>>(sp, nullptr, v0T);

    iter_kernel<1><<<dim3(NKT, 2), 640, 0, stream>>>(xT, Ws, v0T, sp);
    squash_kernel<1><<<320, 256, 0, stream>>>(sp, v0T, vsumT);

    iter_kernel<1><<<dim3(NKT, 2), 640, 0, stream>>>(xT, Ws, vsumT, sp);
    squash_kernel<2><<<320, 256, 0, stream>>>(sp, nullptr, out);
}